// Round 6
// baseline (17.110 us; speedup 1.0000x reference)
//
#include <hip/hip_runtime.h>
#include <math.h>

// Math: per qubit i, theta = w[i] + (i<2 ? x[i] : 0), phi = theta/2.
//   state_i = [cos(phi), -i*sin(phi)]^T   (complex64, (n,2,1))
//   O_i     = cos(theta) = cos^2(phi) - sin^2(phi)   (real)
//
// Harness stores complex64 outputs as float32 REAL PARTS (out_size = 3n):
//   out[2i+0] = cos(phi)    (Re s0)
//   out[2i+1] = 0           (Re s1 = Re(-i sin) = 0)
//   out[2n+i] = cos(theta)  (Re O)
//
// Streaming kernel: 8 MB read, 24 MB write, zero reuse within a call.
// - w load: CACHED (plain load). w is read-only across graph replays and
//   fits in L3 (8 MB << 256 MB) -> repeat replays hit cache, HBM read ~0.
//   (R5 lesson: nt-loading w forced an 8 MB HBM read every replay.)
// - out stores: nontemporal. Write-once data, never re-read by us; skip
//   cache allocation.
// 4 qubits/thread, all accesses 16 B/lane coalesced.

typedef float f4 __attribute__((ext_vector_type(4)));

__global__ __launch_bounds__(256) void qubit_rx4(
    const float* __restrict__ x,
    const float* __restrict__ w,
    float* __restrict__ out,
    int n)  // n % 4 == 0
{
    const int nquads = n >> 2;
    int quad = blockIdx.x * blockDim.x + threadIdx.x;
    if (quad >= nquads) return;

    f4 wv = reinterpret_cast<const f4*>(w)[quad];   // cached load (L3-resident across replays)
    float t0 = wv.x, t1 = wv.y, t2 = wv.z, t3 = wv.w;
    if (quad == 0) { t0 += x[0]; t1 += x[1]; }      // data-encoding on qubits 0,1 only

    float p0 = 0.5f * t0, p1 = 0.5f * t1, p2 = 0.5f * t2, p3 = 0.5f * t3;
    float c0 = __cosf(p0), s0 = __sinf(p0);
    float c1 = __cosf(p1), s1 = __sinf(p1);
    float c2 = __cosf(p2), s2 = __sinf(p2);
    float c3 = __cosf(p3), s3 = __sinf(p3);

    // state block: 2 floats/qubit -> 2 f4 per quad
    f4* st = reinterpret_cast<f4*>(out);
    f4 s_lo = {c0, 0.0f, c1, 0.0f};
    f4 s_hi = {c2, 0.0f, c3, 0.0f};
    __builtin_nontemporal_store(s_lo, st + quad * 2 + 0);
    __builtin_nontemporal_store(s_hi, st + quad * 2 + 1);

    // O block at out + 2n: 1 float/qubit -> 1 f4 per quad
    f4 ov = {c0 * c0 - s0 * s0,
             c1 * c1 - s1 * s1,
             c2 * c2 - s2 * s2,
             c3 * c3 - s3 * s3};
    __builtin_nontemporal_store(ov, reinterpret_cast<f4*>(out + (size_t)2 * n) + quad);
}

extern "C" void kernel_launch(void* const* d_in, const int* in_sizes, int n_in,
                              void* d_out, int out_size, void* d_ws, size_t ws_size,
                              hipStream_t stream) {
    const float* x = (const float*)d_in[0];   // (2,)
    const float* w = (const float*)d_in[1];   // (N_QUBITS,)
    float* out = (float*)d_out;               // 3n floats (real parts of complex64)
    const int n = in_sizes[1];                // 2,000,000

    const int nquads = n >> 2;                // 500,000
    const int block = 256;
    const int grid = (nquads + block - 1) / block;  // 1954
    qubit_rx4<<<grid, block, 0, stream>>>(x, w, out, n);
}

// Round 7
// 12.651 us; speedup vs baseline: 1.3525x; 1.3525x over previous
//
#include <hip/hip_runtime.h>
#include <math.h>

// Math: per qubit i, theta = w[i] + (i<2 ? x[i] : 0), phi = theta/2.
//   state_i = [cos(phi), -i*sin(phi)]^T   (complex64, (n,2,1))
//   O_i     = cos(theta) = cos^2(phi) - sin^2(phi)   (real)
//
// Harness stores complex64 outputs as float32 REAL PARTS (out_size = 3n):
//   out[2i+0] = cos(phi)    (Re s0)
//   out[2i+1] = 0           (Re s1 = Re(-i sin) = 0)
//   out[2n+i] = cos(theta)  (Re O)
//
// R6 lesson: NT stores at block=256 cost +5.5us vs cached stores (R3).
// The 24 MB output fits in the 256 MB L3 -> cached stores absorb at cache
// speed (writeback billed outside the kernel); nt stores pay HBM rate
// synchronously. This round: ALL accesses cached, block=1024 (single
// variable vs R3's block=256 / 11.6us anchor; also isolates R5's confound).

typedef float f4 __attribute__((ext_vector_type(4)));

__global__ __launch_bounds__(1024) void qubit_rx4(
    const float* __restrict__ x,
    const float* __restrict__ w,
    float* __restrict__ out,
    int n)  // n % 4 == 0
{
    const int nquads = n >> 2;
    int quad = blockIdx.x * blockDim.x + threadIdx.x;
    if (quad >= nquads) return;

    f4 wv = reinterpret_cast<const f4*>(w)[quad];   // cached; L3-resident across replays
    float t0 = wv.x, t1 = wv.y, t2 = wv.z, t3 = wv.w;
    if (quad == 0) { t0 += x[0]; t1 += x[1]; }      // data-encoding on qubits 0,1 only

    float p0 = 0.5f * t0, p1 = 0.5f * t1, p2 = 0.5f * t2, p3 = 0.5f * t3;
    float c0 = __cosf(p0), s0 = __sinf(p0);
    float c1 = __cosf(p1), s1 = __sinf(p1);
    float c2 = __cosf(p2), s2 = __sinf(p2);
    float c3 = __cosf(p3), s3 = __sinf(p3);

    // state block: 2 floats/qubit -> 2 f4 per quad (cached stores)
    f4* st = reinterpret_cast<f4*>(out);
    st[quad * 2 + 0] = f4{c0, 0.0f, c1, 0.0f};
    st[quad * 2 + 1] = f4{c2, 0.0f, c3, 0.0f};

    // O block at out + 2n: 1 float/qubit -> 1 f4 per quad
    reinterpret_cast<f4*>(out + (size_t)2 * n)[quad] =
        f4{c0 * c0 - s0 * s0,
           c1 * c1 - s1 * s1,
           c2 * c2 - s2 * s2,
           c3 * c3 - s3 * s3};
}

extern "C" void kernel_launch(void* const* d_in, const int* in_sizes, int n_in,
                              void* d_out, int out_size, void* d_ws, size_t ws_size,
                              hipStream_t stream) {
    const float* x = (const float*)d_in[0];   // (2,)
    const float* w = (const float*)d_in[1];   // (N_QUBITS,)
    float* out = (float*)d_out;               // 3n floats (real parts of complex64)
    const int n = in_sizes[1];                // 2,000,000

    const int nquads = n >> 2;                // 500,000
    const int block = 1024;
    const int grid = (nquads + block - 1) / block;  // 489
    qubit_rx4<<<grid, block, 0, stream>>>(x, w, out, n);
}

// Round 8
// 11.973 us; speedup vs baseline: 1.4291x; 1.0566x over previous
//
#include <hip/hip_runtime.h>
#include <math.h>

// Math: per qubit i, theta = w[i] + (i<2 ? x[i] : 0), phi = theta/2.
//   state_i = [cos(phi), -i*sin(phi)]^T   (complex64, (n,2,1))
//   O_i     = cos(theta) = cos^2(phi) - sin^2(phi)   (real)
//
// Harness stores complex64 outputs as float32 REAL PARTS (out_size = 3n):
//   out[2i+0] = cos(phi)    (Re s0)
//   out[2i+1] = 0           (Re s1 = Re(-i sin) = 0)
//   out[2n+i] = cos(theta)  (Re O)
//
// Session conclusion (R2-R7 single-variable matrix): all configs land at
// 11.4-12.7 us; floor = ~5-6 us fixed graph-replay/launch overhead +
// ~5 us BW-bound work (32 MB @ ~6.5 TB/s). This is the best-measured
// config (R5): block=1024, nt load + nt stores, 4 qubits/thread,
// all accesses 16 B/lane coalesced.

typedef float f4 __attribute__((ext_vector_type(4)));

__global__ __launch_bounds__(1024) void qubit_rx4_nt(
    const float* __restrict__ x,
    const float* __restrict__ w,
    float* __restrict__ out,
    int n)  // n % 4 == 0
{
    const int nquads = n >> 2;
    int quad = blockIdx.x * blockDim.x + threadIdx.x;
    if (quad >= nquads) return;

    f4 wv = __builtin_nontemporal_load(reinterpret_cast<const f4*>(w) + quad);
    float t0 = wv.x, t1 = wv.y, t2 = wv.z, t3 = wv.w;
    if (quad == 0) { t0 += x[0]; t1 += x[1]; }  // data-encoding on qubits 0,1 only

    float p0 = 0.5f * t0, p1 = 0.5f * t1, p2 = 0.5f * t2, p3 = 0.5f * t3;
    float c0 = __cosf(p0), s0 = __sinf(p0);
    float c1 = __cosf(p1), s1 = __sinf(p1);
    float c2 = __cosf(p2), s2 = __sinf(p2);
    float c3 = __cosf(p3), s3 = __sinf(p3);

    // state block: 2 floats/qubit -> 2 f4 per quad
    f4* st = reinterpret_cast<f4*>(out);
    f4 s_lo = {c0, 0.0f, c1, 0.0f};
    f4 s_hi = {c2, 0.0f, c3, 0.0f};
    __builtin_nontemporal_store(s_lo, st + quad * 2 + 0);
    __builtin_nontemporal_store(s_hi, st + quad * 2 + 1);

    // O block at out + 2n: 1 float/qubit -> 1 f4 per quad
    f4 ov = {c0 * c0 - s0 * s0,
             c1 * c1 - s1 * s1,
             c2 * c2 - s2 * s2,
             c3 * c3 - s3 * s3};
    __builtin_nontemporal_store(ov, reinterpret_cast<f4*>(out + (size_t)2 * n) + quad);
}

extern "C" void kernel_launch(void* const* d_in, const int* in_sizes, int n_in,
                              void* d_out, int out_size, void* d_ws, size_t ws_size,
                              hipStream_t stream) {
    const float* x = (const float*)d_in[0];   // (2,)
    const float* w = (const float*)d_in[1];   // (N_QUBITS,)
    float* out = (float*)d_out;               // 3n floats (real parts of complex64)
    const int n = in_sizes[1];                // 2,000,000

    const int nquads = n >> 2;                // 500,000
    const int block = 1024;
    const int grid = (nquads + block - 1) / block;  // 489
    qubit_rx4_nt<<<grid, block, 0, stream>>>(x, w, out, n);
}